// Round 1
// baseline (246.485 us; speedup 1.0000x reference)
//
#include <hip/hip_runtime.h>
#include <hip/hip_bf16.h>
#include <math.h>

#define DIM 1024
#define NB  4096      // B
#define N2  8192      // 2B
#define BM  128
#define BK  64
#define NT  64        // N2 / BM

typedef float  f32x4  __attribute__((ext_vector_type(4)));
typedef __bf16 bf16x8 __attribute__((ext_vector_type(8)));

__device__ __forceinline__ void gload_lds16(const __hip_bfloat16* g, __hip_bfloat16* l) {
    __builtin_amdgcn_global_load_lds((__attribute__((address_space(1))) void*)(g),
                                     (__attribute__((address_space(3))) void*)(l),
                                     16, 0, 0);
}

// ---------------- Kernel 1: normalize rows, emit bf16 z, positives ----------
__global__ __launch_bounds__(256) void norm_kernel(
    const float* __restrict__ p1, const float* __restrict__ p2,
    __hip_bfloat16* __restrict__ zb, float* __restrict__ pos)
{
    const int r = blockIdx.x;         // 0..4095 (row pair)
    const int t = threadIdx.x;        // 0..255, 4 floats each
    const float4 x1 = ((const float4*)(p1 + (size_t)r * DIM))[t];
    const float4 x2 = ((const float4*)(p2 + (size_t)r * DIM))[t];
    float s1  = x1.x*x1.x + x1.y*x1.y + x1.z*x1.z + x1.w*x1.w;
    float s2  = x2.x*x2.x + x2.y*x2.y + x2.z*x2.z + x2.w*x2.w;
    float s12 = x1.x*x2.x + x1.y*x2.y + x1.z*x2.z + x1.w*x2.w;
#pragma unroll
    for (int off = 1; off < 64; off <<= 1) {
        s1  += __shfl_xor(s1,  off);
        s2  += __shfl_xor(s2,  off);
        s12 += __shfl_xor(s12, off);
    }
    __shared__ float ls[3][4];
    const int wid = t >> 6;
    if ((t & 63) == 0) { ls[0][wid] = s1; ls[1][wid] = s2; ls[2][wid] = s12; }
    __syncthreads();
    s1  = ls[0][0] + ls[0][1] + ls[0][2] + ls[0][3];
    s2  = ls[1][0] + ls[1][1] + ls[1][2] + ls[1][3];
    s12 = ls[2][0] + ls[2][1] + ls[2][2] + ls[2][3];
    const float rn1 = 1.0f / fmaxf(sqrtf(s1), 1e-12f);
    const float rn2 = 1.0f / fmaxf(sqrtf(s2), 1e-12f);
    if (t == 0) pos[r] = s12 * rn1 * rn2;

    union { ushort4 u; __hip_bfloat16 h[4]; } o1, o2;
    o1.h[0] = __float2bfloat16(x1.x * rn1); o1.h[1] = __float2bfloat16(x1.y * rn1);
    o1.h[2] = __float2bfloat16(x1.z * rn1); o1.h[3] = __float2bfloat16(x1.w * rn1);
    o2.h[0] = __float2bfloat16(x2.x * rn2); o2.h[1] = __float2bfloat16(x2.y * rn2);
    o2.h[2] = __float2bfloat16(x2.z * rn2); o2.h[3] = __float2bfloat16(x2.w * rn2);
    ((ushort4*)zb)[(size_t)r * 256 + t]        = o1.u;   // z_i row r
    ((ushort4*)zb)[(size_t)(NB + r) * 256 + t] = o2.u;   // z_j row r
}

// ------- Kernel 2: fused z·z^T tile GEMM + exp row-sums + lunif partials ----
__global__ __launch_bounds__(256) void sim_kernel(
    const __hip_bfloat16* __restrict__ zb,
    float* __restrict__ partials,    // [N2][NT] per-(row, col-tile) exp sums
    float* __restrict__ lup)         // [NT*NT] per-tile lunif partials
{
    __shared__ __align__(16) __hip_bfloat16 As[BM * BK];
    __shared__ __align__(16) __hip_bfloat16 Bs[BM * BK];
    __shared__ float rowsum[BM];
    __shared__ float lured[4];

    const int bid = blockIdx.x;
    const int swz = ((bid & 7) << 9) | (bid >> 3);   // bijective XCD swizzle (4096%8==0)
    const int rt = swz >> 6;
    const int ct = swz & 63;
    const int t    = threadIdx.x;
    const int lane = t & 63;
    const int wid  = t >> 6;
    const int wr   = wid >> 1;        // 2x2 wave grid, each wave 64x64 out
    const int wc   = wid & 1;
    const int row0 = rt * BM;
    const int col0 = ct * BM;

    if (t < BM) rowsum[t] = 0.0f;

    f32x4 acc[4][4] = {};

    const int fr   = lane & 15;          // fragment row/col within 16
    const int koff = (lane >> 4) << 3;   // k sub-offset 0,8,16,24

    for (int kt = 0; kt < DIM / BK; ++kt) {
        const int k0 = kt * BK;
        // stage A (rows) and B (cols) tiles: 16 chunks of 1024B each, 4/wave
#pragma unroll
        for (int c = 0; c < 4; ++c) {
            const int ch   = (wid << 2) | c;
            const int e    = (ch << 9) + (lane << 3);   // elem offset in tile
            const int trow = e >> 6;
            const int tcol = e & 63;
            gload_lds16(zb + (size_t)(row0 + trow) * DIM + k0 + tcol, &As[ch << 9]);
            gload_lds16(zb + (size_t)(col0 + trow) * DIM + k0 + tcol, &Bs[ch << 9]);
        }
        __syncthreads();

        bf16x8 af[4][2], bv[4][2];
#pragma unroll
        for (int m = 0; m < 4; ++m) {
#pragma unroll
            for (int ks = 0; ks < 2; ++ks) {
                af[m][ks] = *(const bf16x8*)&As[((wr << 6) + (m << 4) + fr) * BK + (ks << 5) + koff];
                bv[m][ks] = *(const bf16x8*)&Bs[((wc << 6) + (m << 4) + fr) * BK + (ks << 5) + koff];
            }
        }
#pragma unroll
        for (int m = 0; m < 4; ++m) {
#pragma unroll
            for (int n = 0; n < 4; ++n) {
                acc[m][n] = __builtin_amdgcn_mfma_f32_16x16x32_bf16(af[m][0], bv[n][0], acc[m][n], 0, 0, 0);
                acc[m][n] = __builtin_amdgcn_mfma_f32_16x16x32_bf16(af[m][1], bv[n][1], acc[m][n], 0, 0, 0);
            }
        }
        __syncthreads();
    }

    // ---- epilogue: C/D layout col=lane&15, row=(lane>>4)*4+reg (verified) ----
    const int  rsub  = (lane >> 4) << 2;
    const int  csub  = lane & 15;
    const bool reg1  = (rt < 16) && (ct < 16);                       // z_i[:2048]
    const bool reg2  = (rt >= 16) && (rt < 32) && (ct >= 16) && (ct < 32); // z_i[2048:]
    const bool inreg = reg1 || reg2;
    const int  rbase = row0 + (wr << 6);
    const int  cbase = col0 + (wc << 6);

    float lu = 0.0f;
#pragma unroll
    for (int m = 0; m < 4; ++m) {
        float rs[4] = {0.0f, 0.0f, 0.0f, 0.0f};
#pragma unroll
        for (int n = 0; n < 4; ++n) {
            const int gcol = cbase + (n << 4) + csub;
#pragma unroll
            for (int r = 0; r < 4; ++r) {
                const int grow = rbase + (m << 4) + rsub + r;
                const float s = acc[m][n][r];
                float e = __expf(10.0f * s);
                e = (grow != gcol) ? e : 0.0f;   // exclude diagonal
                rs[r] += e;
                if (inreg && (gcol > grow)) {    // strict upper triangle
                    const float d2 = fmaxf(2.0f - 2.0f * s, 0.0f);
                    lu += __expf(-2.0f * d2);
                }
            }
        }
        // reduce across the 16 lanes sharing (lane>>4): full 64-col row sums
#pragma unroll
        for (int off = 1; off < 16; off <<= 1) {
#pragma unroll
            for (int r = 0; r < 4; ++r) rs[r] += __shfl_xor(rs[r], off);
        }
        if ((lane & 15) == 0) {
#pragma unroll
            for (int r = 0; r < 4; ++r)
                atomicAdd(&rowsum[(wr << 6) + (m << 4) + rsub + r], rs[r]); // 2 adds/slot: commutative
        }
    }
#pragma unroll
    for (int off = 1; off < 64; off <<= 1) lu += __shfl_xor(lu, off);
    if (lane == 0) lured[wid] = lu;
    __syncthreads();
    if (t == 0) lup[(rt << 6) | ct] = lured[0] + lured[1] + lured[2] + lured[3];
    if (t < BM) partials[(size_t)(row0 + t) * NT + ct] = rowsum[t];
}

// --------- Kernel 3a: per-row denom -> log, 128 rows per block --------------
__global__ __launch_bounds__(128) void logred_kernel(
    const float* __restrict__ partials, double* __restrict__ red_log)
{
    const int t   = threadIdx.x;
    const int row = blockIdx.x * 128 + t;
    const float* p = partials + (size_t)row * NT;
    float dsum = 0.0f;
#pragma unroll
    for (int i = 0; i < NT; ++i) dsum += p[i];
    double l = log((double)dsum);
    __shared__ double sd[128];
    sd[t] = l;
    __syncthreads();
    for (int s = 64; s > 0; s >>= 1) {
        if (t < s) sd[t] += sd[t + s];
        __syncthreads();
    }
    if (t == 0) red_log[blockIdx.x] = sd[0];
}

// --------- Kernel 3b: final scalars --------------------------------------
__global__ __launch_bounds__(256) void final_kernel(
    const double* __restrict__ red_log, const float* __restrict__ pos,
    const float* __restrict__ lup, float* __restrict__ out)
{
    const int t = threadIdx.x;
    double dlog = 0.0, dpos = 0.0, ds1 = 0.0, ds2 = 0.0;
    if (t < 64) dlog = red_log[t];
    for (int i = t; i < NB; i += 256) dpos += (double)pos[i];
    for (int i = t; i < NT * NT; i += 256) {
        const int rt = i >> 6, ct = i & 63;
        const double v = (double)lup[i];
        if (rt < 16 && ct < 16) ds1 += v;
        else if (rt >= 16 && rt < 32 && ct >= 16 && ct < 32) ds2 += v;
    }
    __shared__ double sd[4][256];
    sd[0][t] = dlog; sd[1][t] = dpos; sd[2][t] = ds1; sd[3][t] = ds2;
    __syncthreads();
    for (int s = 128; s > 0; s >>= 1) {
        if (t < s) {
            sd[0][t] += sd[0][t + s]; sd[1][t] += sd[1][t + s];
            sd[2][t] += sd[2][t + s]; sd[3][t] += sd[3][t + s];
        }
        __syncthreads();
    }
    if (t == 0) {
        const double mean_pos = sd[1][0] / (double)NB;
        const double loss   = sd[0][0] / (double)N2 - mean_pos * 10.0;   // /TEMP
        const double lalign = 2.0 - 2.0 * mean_pos;
        const double C      = 2048.0 * 2047.0 * 0.5;
        const double lunif  = 0.5 * (log(sd[2][0] / C) + log(sd[3][0] / C));
        out[0] = (float)loss;
        out[1] = (float)lalign;
        out[2] = (float)lunif;
    }
}

extern "C" void kernel_launch(void* const* d_in, const int* in_sizes, int n_in,
                              void* d_out, int out_size, void* d_ws, size_t ws_size,
                              hipStream_t stream) {
    const float* p1 = (const float*)d_in[0];
    const float* p2 = (const float*)d_in[1];
    float* out = (float*)d_out;

    char* ws = (char*)d_ws;
    __hip_bfloat16* zb = (__hip_bfloat16*)ws;                          // 16 MB
    float*  partials   = (float*)(ws + ((size_t)16 << 20));            // 2 MB
    float*  pos        = (float*)(ws + ((size_t)18 << 20));            // 16 KB
    float*  lup        = (float*)(ws + ((size_t)18 << 20) + 16384);    // 16 KB
    double* red_log    = (double*)(ws + ((size_t)18 << 20) + 32768);   // 512 B

    hipLaunchKernelGGL(norm_kernel,  dim3(NB),      dim3(256), 0, stream, p1, p2, zb, pos);
    hipLaunchKernelGGL(sim_kernel,   dim3(NT * NT), dim3(256), 0, stream, zb, partials, lup);
    hipLaunchKernelGGL(logred_kernel, dim3(64),     dim3(128), 0, stream, partials, red_log);
    hipLaunchKernelGGL(final_kernel, dim3(1),       dim3(256), 0, stream, red_log, pos, lup, out);
}

// Round 2
// 219.376 us; speedup vs baseline: 1.1236x; 1.1236x over previous
//
#include <hip/hip_runtime.h>
#include <hip/hip_bf16.h>
#include <math.h>

#define DIM 1024
#define NB  4096      // B
#define N2  8192      // 2B
#define BM  128
#define BK  64
#define NT  64        // N2 / BM

typedef float  f32x4  __attribute__((ext_vector_type(4)));
typedef __bf16 bf16x8 __attribute__((ext_vector_type(8)));

__device__ __forceinline__ void gload_lds16(const __hip_bfloat16* g, __hip_bfloat16* l) {
    __builtin_amdgcn_global_load_lds((__attribute__((address_space(1))) void*)(g),
                                     (__attribute__((address_space(3))) void*)(l),
                                     16, 0, 0);
}

// ---------------- Kernel 1: normalize rows, emit bf16 z, positives ----------
__global__ __launch_bounds__(256) void norm_kernel(
    const float* __restrict__ p1, const float* __restrict__ p2,
    __hip_bfloat16* __restrict__ zb, float* __restrict__ pos)
{
    const int r = blockIdx.x;         // 0..4095 (row pair)
    const int t = threadIdx.x;        // 0..255, 4 floats each
    const float4 x1 = ((const float4*)(p1 + (size_t)r * DIM))[t];
    const float4 x2 = ((const float4*)(p2 + (size_t)r * DIM))[t];
    float s1  = x1.x*x1.x + x1.y*x1.y + x1.z*x1.z + x1.w*x1.w;
    float s2  = x2.x*x2.x + x2.y*x2.y + x2.z*x2.z + x2.w*x2.w;
    float s12 = x1.x*x2.x + x1.y*x2.y + x1.z*x2.z + x1.w*x2.w;
#pragma unroll
    for (int off = 1; off < 64; off <<= 1) {
        s1  += __shfl_xor(s1,  off);
        s2  += __shfl_xor(s2,  off);
        s12 += __shfl_xor(s12, off);
    }
    __shared__ float ls[3][4];
    const int wid = t >> 6;
    if ((t & 63) == 0) { ls[0][wid] = s1; ls[1][wid] = s2; ls[2][wid] = s12; }
    __syncthreads();
    s1  = ls[0][0] + ls[0][1] + ls[0][2] + ls[0][3];
    s2  = ls[1][0] + ls[1][1] + ls[1][2] + ls[1][3];
    s12 = ls[2][0] + ls[2][1] + ls[2][2] + ls[2][3];
    const float rn1 = 1.0f / fmaxf(sqrtf(s1), 1e-12f);
    const float rn2 = 1.0f / fmaxf(sqrtf(s2), 1e-12f);
    if (t == 0) pos[r] = s12 * rn1 * rn2;

    union { ushort4 u; __hip_bfloat16 h[4]; } o1, o2;
    o1.h[0] = __float2bfloat16(x1.x * rn1); o1.h[1] = __float2bfloat16(x1.y * rn1);
    o1.h[2] = __float2bfloat16(x1.z * rn1); o1.h[3] = __float2bfloat16(x1.w * rn1);
    o2.h[0] = __float2bfloat16(x2.x * rn2); o2.h[1] = __float2bfloat16(x2.y * rn2);
    o2.h[2] = __float2bfloat16(x2.z * rn2); o2.h[3] = __float2bfloat16(x2.w * rn2);
    ((ushort4*)zb)[(size_t)r * 256 + t]        = o1.u;   // z_i row r
    ((ushort4*)zb)[(size_t)(NB + r) * 256 + t] = o2.u;   // z_j row r
}

// ------- Kernel 2: fused z·z^T tile GEMM + exp row-sums + lunif partials ----
// LDS layout: XOR-swizzled st-16-style — logical (row, byte-col c) lives at
// lds byte row*128 + (c ^ ((row&7)<<4)).  global_load_lds writes LINEARLY,
// so the GLOBAL source column is pre-permuted to the inverse (same involution),
// and ds_read applies the XOR.  Breaks the 16-way stride-128B conflict -> 2-way.
__global__ __launch_bounds__(256) void sim_kernel(
    const __hip_bfloat16* __restrict__ zb,
    float* __restrict__ partials,    // [N2][NT] per-(row, col-tile) exp sums
    float* __restrict__ lup)         // [NT*NT] per-tile lunif partials
{
    __shared__ __align__(16) __hip_bfloat16 As[BM * BK];
    __shared__ __align__(16) __hip_bfloat16 Bs[BM * BK];
    __shared__ float rowsum[BM];
    __shared__ float lured[4];

    const int bid = blockIdx.x;
    const int swz = ((bid & 7) << 9) | (bid >> 3);   // bijective XCD swizzle (4096%8==0)
    const int rt = swz >> 6;
    const int ct = swz & 63;
    const int t    = threadIdx.x;
    const int lane = t & 63;
    const int wid  = t >> 6;
    const int wr   = wid >> 1;        // 2x2 wave grid, each wave 64x64 out
    const int wc   = wid & 1;
    const int row0 = rt * BM;
    const int col0 = ct * BM;

    if (t < BM) rowsum[t] = 0.0f;

    f32x4 acc[4][4] = {};

    const int fr   = lane & 15;              // fragment row within 16
    const int xorb = (fr & 7) << 4;          // swizzle XOR for this lane's rows
    const int g16  = (lane >> 4) << 4;       // k sub-offset in bytes (0,16,32,48)
    // pre-swizzled global source column for staging (elements):
    const int tcol = (((lane & 7) ^ ((lane >> 3) & 7)) << 3);
    const int lrow = lane >> 3;              // 0..7 row-within-chunk

    for (int kt = 0; kt < DIM / BK; ++kt) {
        const int k0 = kt * BK;
        // stage A (rows) and B (cols) tiles: 16 chunks of 1024B each, 4/wave
#pragma unroll
        for (int c = 0; c < 4; ++c) {
            const int ch   = (wid << 2) | c;
            const int trow = (ch << 3) + lrow;
            gload_lds16(zb + (size_t)(row0 + trow) * DIM + k0 + tcol, &As[ch << 9]);
            gload_lds16(zb + (size_t)(col0 + trow) * DIM + k0 + tcol, &Bs[ch << 9]);
        }
        __syncthreads();

        const char* Ab = (const char*)As + (((wr << 6) + fr) << 7);
        const char* Bb = (const char*)Bs + (((wc << 6) + fr) << 7);
        bf16x8 af[4][2], bv[4][2];
#pragma unroll
        for (int m = 0; m < 4; ++m) {
#pragma unroll
            for (int ks = 0; ks < 2; ++ks) {
                const int cb = ((ks << 6) | g16) ^ xorb;
                af[m][ks] = *(const bf16x8*)(Ab + (m << 11) + cb);
                bv[m][ks] = *(const bf16x8*)(Bb + (m << 11) + cb);
            }
        }
#pragma unroll
        for (int m = 0; m < 4; ++m) {
#pragma unroll
            for (int n = 0; n < 4; ++n) {
                acc[m][n] = __builtin_amdgcn_mfma_f32_16x16x32_bf16(af[m][0], bv[n][0], acc[m][n], 0, 0, 0);
                acc[m][n] = __builtin_amdgcn_mfma_f32_16x16x32_bf16(af[m][1], bv[n][1], acc[m][n], 0, 0, 0);
            }
        }
        __syncthreads();
    }

    // ---- epilogue: C/D layout col=lane&15, row=(lane>>4)*4+reg (verified) ----
    const int  rsub  = (lane >> 4) << 2;
    const int  csub  = lane & 15;
    const bool reg1  = (rt < 16) && (ct < 16);                       // z_i[:2048]
    const bool reg2  = (rt >= 16) && (rt < 32) && (ct >= 16) && (ct < 32); // z_i[2048:]
    const bool inreg = reg1 || reg2;
    const int  rbase = row0 + (wr << 6);
    const int  cbase = col0 + (wc << 6);

    float lu = 0.0f;
#pragma unroll
    for (int m = 0; m < 4; ++m) {
        float rs[4] = {0.0f, 0.0f, 0.0f, 0.0f};
#pragma unroll
        for (int n = 0; n < 4; ++n) {
            const int gcol = cbase + (n << 4) + csub;
#pragma unroll
            for (int r = 0; r < 4; ++r) {
                const int grow = rbase + (m << 4) + rsub + r;
                const float s = acc[m][n][r];
                float e = __expf(10.0f * s);
                e = (grow != gcol) ? e : 0.0f;   // exclude diagonal
                rs[r] += e;
                if (inreg && (gcol > grow)) {    // strict upper triangle
                    const float d2 = fmaxf(2.0f - 2.0f * s, 0.0f);
                    lu += __expf(-2.0f * d2);
                }
            }
        }
        // reduce across the 16 lanes sharing (lane>>4): full 64-col row sums
#pragma unroll
        for (int off = 1; off < 16; off <<= 1) {
#pragma unroll
            for (int r = 0; r < 4; ++r) rs[r] += __shfl_xor(rs[r], off);
        }
        if ((lane & 15) == 0) {
#pragma unroll
            for (int r = 0; r < 4; ++r)
                atomicAdd(&rowsum[(wr << 6) + (m << 4) + rsub + r], rs[r]); // 2 adds/slot: commutative
        }
    }
#pragma unroll
    for (int off = 1; off < 64; off <<= 1) lu += __shfl_xor(lu, off);
    if (lane == 0) lured[wid] = lu;
    __syncthreads();
    if (t == 0) lup[(rt << 6) | ct] = lured[0] + lured[1] + lured[2] + lured[3];
    if (t < BM) partials[(size_t)(row0 + t) * NT + ct] = rowsum[t];
}

// --------- Kernel 3a: per-row denom -> log, 128 rows per block --------------
__global__ __launch_bounds__(128) void logred_kernel(
    const float* __restrict__ partials, double* __restrict__ red_log)
{
    const int t   = threadIdx.x;
    const int row = blockIdx.x * 128 + t;
    const float* p = partials + (size_t)row * NT;
    float dsum = 0.0f;
#pragma unroll
    for (int i = 0; i < NT; ++i) dsum += p[i];
    double l = log((double)dsum);
    __shared__ double sd[128];
    sd[t] = l;
    __syncthreads();
    for (int s = 64; s > 0; s >>= 1) {
        if (t < s) sd[t] += sd[t + s];
        __syncthreads();
    }
    if (t == 0) red_log[blockIdx.x] = sd[0];
}

// --------- Kernel 3b: final scalars --------------------------------------
__global__ __launch_bounds__(256) void final_kernel(
    const double* __restrict__ red_log, const float* __restrict__ pos,
    const float* __restrict__ lup, float* __restrict__ out)
{
    const int t = threadIdx.x;
    double dlog = 0.0, dpos = 0.0, ds1 = 0.0, ds2 = 0.0;
    if (t < 64) dlog = red_log[t];
    for (int i = t; i < NB; i += 256) dpos += (double)pos[i];
    for (int i = t; i < NT * NT; i += 256) {
        const int rt = i >> 6, ct = i & 63;
        const double v = (double)lup[i];
        if (rt < 16 && ct < 16) ds1 += v;
        else if (rt >= 16 && rt < 32 && ct >= 16 && ct < 32) ds2 += v;
    }
    __shared__ double sd[4][256];
    sd[0][t] = dlog; sd[1][t] = dpos; sd[2][t] = ds1; sd[3][t] = ds2;
    __syncthreads();
    for (int s = 128; s > 0; s >>= 1) {
        if (t < s) {
            sd[0][t] += sd[0][t + s]; sd[1][t] += sd[1][t + s];
            sd[2][t] += sd[2][t + s]; sd[3][t] += sd[3][t + s];
        }
        __syncthreads();
    }
    if (t == 0) {
        const double mean_pos = sd[1][0] / (double)NB;
        const double loss   = sd[0][0] / (double)N2 - mean_pos * 10.0;   // /TEMP
        const double lalign = 2.0 - 2.0 * mean_pos;
        const double C      = 2048.0 * 2047.0 * 0.5;
        const double lunif  = 0.5 * (log(sd[2][0] / C) + log(sd[3][0] / C));
        out[0] = (float)loss;
        out[1] = (float)lalign;
        out[2] = (float)lunif;
    }
}

extern "C" void kernel_launch(void* const* d_in, const int* in_sizes, int n_in,
                              void* d_out, int out_size, void* d_ws, size_t ws_size,
                              hipStream_t stream) {
    const float* p1 = (const float*)d_in[0];
    const float* p2 = (const float*)d_in[1];
    float* out = (float*)d_out;

    char* ws = (char*)d_ws;
    __hip_bfloat16* zb = (__hip_bfloat16*)ws;                          // 16 MB
    float*  partials   = (float*)(ws + ((size_t)16 << 20));            // 2 MB
    float*  pos        = (float*)(ws + ((size_t)18 << 20));            // 16 KB
    float*  lup        = (float*)(ws + ((size_t)18 << 20) + 16384);    // 16 KB
    double* red_log    = (double*)(ws + ((size_t)18 << 20) + 32768);   // 512 B

    hipLaunchKernelGGL(norm_kernel,  dim3(NB),      dim3(256), 0, stream, p1, p2, zb, pos);
    hipLaunchKernelGGL(sim_kernel,   dim3(NT * NT), dim3(256), 0, stream, zb, partials, lup);
    hipLaunchKernelGGL(logred_kernel, dim3(64),     dim3(128), 0, stream, partials, red_log);
    hipLaunchKernelGGL(final_kernel, dim3(1),       dim3(256), 0, stream, red_log, pos, lup, out);
}

// Round 3
// 145.368 us; speedup vs baseline: 1.6956x; 1.5091x over previous
//
#include <hip/hip_runtime.h>
#include <hip/hip_bf16.h>
#include <math.h>

#define DIM 1024
#define NB  4096      // B
#define N2  8192      // 2B
#define BM  128
#define BK  64
#define NT  64        // N2 / BM
#define NTILES 2080   // NT*(NT+1)/2 upper-triangular tiles

typedef float  f32x4  __attribute__((ext_vector_type(4)));
typedef __bf16 bf16x8 __attribute__((ext_vector_type(8)));

__device__ __forceinline__ void gload_lds16(const __hip_bfloat16* g, __hip_bfloat16* l) {
    __builtin_amdgcn_global_load_lds((__attribute__((address_space(1))) void*)(g),
                                     (__attribute__((address_space(3))) void*)(l),
                                     16, 0, 0);
}

// ---------------- Kernel 1: normalize rows, emit bf16 z, positives ----------
__global__ __launch_bounds__(256) void norm_kernel(
    const float* __restrict__ p1, const float* __restrict__ p2,
    __hip_bfloat16* __restrict__ zb, float* __restrict__ pos)
{
    const int r = blockIdx.x;         // 0..4095 (row pair)
    const int t = threadIdx.x;        // 0..255, 4 floats each
    const float4 x1 = ((const float4*)(p1 + (size_t)r * DIM))[t];
    const float4 x2 = ((const float4*)(p2 + (size_t)r * DIM))[t];
    float s1  = x1.x*x1.x + x1.y*x1.y + x1.z*x1.z + x1.w*x1.w;
    float s2  = x2.x*x2.x + x2.y*x2.y + x2.z*x2.z + x2.w*x2.w;
    float s12 = x1.x*x2.x + x1.y*x2.y + x1.z*x2.z + x1.w*x2.w;
#pragma unroll
    for (int off = 1; off < 64; off <<= 1) {
        s1  += __shfl_xor(s1,  off);
        s2  += __shfl_xor(s2,  off);
        s12 += __shfl_xor(s12, off);
    }
    __shared__ float ls[3][4];
    const int wid = t >> 6;
    if ((t & 63) == 0) { ls[0][wid] = s1; ls[1][wid] = s2; ls[2][wid] = s12; }
    __syncthreads();
    s1  = ls[0][0] + ls[0][1] + ls[0][2] + ls[0][3];
    s2  = ls[1][0] + ls[1][1] + ls[1][2] + ls[1][3];
    s12 = ls[2][0] + ls[2][1] + ls[2][2] + ls[2][3];
    const float rn1 = 1.0f / fmaxf(sqrtf(s1), 1e-12f);
    const float rn2 = 1.0f / fmaxf(sqrtf(s2), 1e-12f);
    if (t == 0) pos[r] = s12 * rn1 * rn2;

    union { ushort4 u; __hip_bfloat16 h[4]; } o1, o2;
    o1.h[0] = __float2bfloat16(x1.x * rn1); o1.h[1] = __float2bfloat16(x1.y * rn1);
    o1.h[2] = __float2bfloat16(x1.z * rn1); o1.h[3] = __float2bfloat16(x1.w * rn1);
    o2.h[0] = __float2bfloat16(x2.x * rn2); o2.h[1] = __float2bfloat16(x2.y * rn2);
    o2.h[2] = __float2bfloat16(x2.z * rn2); o2.h[3] = __float2bfloat16(x2.w * rn2);
    ((ushort4*)zb)[(size_t)r * 256 + t]        = o1.u;   // z_i row r
    ((ushort4*)zb)[(size_t)(NB + r) * 256 + t] = o2.u;   // z_j row r
}

// ------- Kernel 2: fused z·z^T SYMMETRIC tile GEMM + exp sums + lunif -------
// Only upper-triangular tiles (rt<=ct) are computed. Off-diagonal tiles emit
// BOTH row-sums (-> partials[rows of rt][ct]) and column-sums (symmetry ->
// partials[rows of ct][rt]). LDS XOR-swizzled st-16-style (both-sides: linear
// gload_lds dest + pre-permuted global col + XOR'd ds_read) -> 0 conflicts.
__global__ __launch_bounds__(256) void sim_kernel(
    const __hip_bfloat16* __restrict__ zb,
    float* __restrict__ partials,    // [N2][NT] per-(row, col-tile) exp sums
    float* __restrict__ lup)         // [NT*NT] per-tile lunif partials (rt<=ct only)
{
    __shared__ __align__(16) __hip_bfloat16 As[BM * BK];
    __shared__ __align__(16) __hip_bfloat16 Bs[BM * BK];
    __shared__ float rowsum[BM];
    __shared__ float colsum[BM];
    __shared__ float lured[4];

    const int bid = blockIdx.x;
    const int i = (bid & 7) * (NTILES / 8) + (bid >> 3);   // bijective XCD chunking (2080%8==0)
    // triangular decode: i -> (rt, ct) with rt<=ct; start(rt) = rt*64 - rt(rt-1)/2
    int rt = (int)(64.5f - sqrtf(64.5f * 64.5f - 2.0f * (float)i));
    if (rt < 0) rt = 0;
    if (rt > 63) rt = 63;
    while (rt > 0 && rt * 64 - ((rt * (rt - 1)) >> 1) > i) --rt;
    while ((rt + 1) * 64 - (((rt + 1) * rt) >> 1) <= i) ++rt;
    const int ct = rt + i - (rt * 64 - ((rt * (rt - 1)) >> 1));
    const bool isdiag = (rt == ct);

    const int t    = threadIdx.x;
    const int lane = t & 63;
    const int wid  = t >> 6;
    const int wr   = wid >> 1;        // 2x2 wave grid, each wave 64x64 out
    const int wc   = wid & 1;
    const int row0 = rt * BM;
    const int col0 = ct * BM;

    if (t < BM) rowsum[t] = 0.0f;
    else        colsum[t - BM] = 0.0f;

    f32x4 acc[4][4] = {};

    const int fr   = lane & 15;              // fragment row within 16
    const int xorb = (fr & 7) << 4;          // swizzle XOR for this lane's rows
    const int g16  = (lane >> 4) << 4;       // k sub-offset in bytes (0,16,32,48)
    const int tcol = (((lane & 7) ^ ((lane >> 3) & 7)) << 3);  // pre-swizzled global col
    const int lrow = lane >> 3;              // 0..7 row-within-chunk

    for (int kt = 0; kt < DIM / BK; ++kt) {
        const int k0 = kt * BK;
#pragma unroll
        for (int c = 0; c < 4; ++c) {
            const int ch   = (wid << 2) | c;
            const int trow = (ch << 3) + lrow;
            gload_lds16(zb + (size_t)(row0 + trow) * DIM + k0 + tcol, &As[ch << 9]);
            gload_lds16(zb + (size_t)(col0 + trow) * DIM + k0 + tcol, &Bs[ch << 9]);
        }
        __syncthreads();

        const char* Ab = (const char*)As + (((wr << 6) + fr) << 7);
        const char* Bb = (const char*)Bs + (((wc << 6) + fr) << 7);
        bf16x8 af[4][2], bv[4][2];
#pragma unroll
        for (int m = 0; m < 4; ++m) {
#pragma unroll
            for (int ks = 0; ks < 2; ++ks) {
                const int cb = ((ks << 6) | g16) ^ xorb;
                af[m][ks] = *(const bf16x8*)(Ab + (m << 11) + cb);
                bv[m][ks] = *(const bf16x8*)(Bb + (m << 11) + cb);
            }
        }
#pragma unroll
        for (int m = 0; m < 4; ++m) {
#pragma unroll
            for (int n = 0; n < 4; ++n) {
                acc[m][n] = __builtin_amdgcn_mfma_f32_16x16x32_bf16(af[m][0], bv[n][0], acc[m][n], 0, 0, 0);
                acc[m][n] = __builtin_amdgcn_mfma_f32_16x16x32_bf16(af[m][1], bv[n][1], acc[m][n], 0, 0, 0);
            }
        }
        __syncthreads();
    }

    // ---- epilogue: C/D layout col=lane&15, row=(lane>>4)*4+reg (verified) ----
    const int  rsub  = (lane >> 4) << 2;
    const int  csub  = lane & 15;
    const bool inreg = (ct < 16) || (rt >= 16 && ct >= 16 && ct < 32); // rt<=ct implies rt<16 / rt in [16,32)
    const int  rbase = row0 + (wr << 6);
    const int  cbase = col0 + (wc << 6);

    float lu = 0.0f;
    float cs[4] = {0.0f, 0.0f, 0.0f, 0.0f};
#pragma unroll
    for (int m = 0; m < 4; ++m) {
        float rs[4] = {0.0f, 0.0f, 0.0f, 0.0f};
#pragma unroll
        for (int n = 0; n < 4; ++n) {
            const int gcol = cbase + (n << 4) + csub;
#pragma unroll
            for (int r = 0; r < 4; ++r) {
                const int grow = rbase + (m << 4) + rsub + r;
                const float s = acc[m][n][r];
                float e = __expf(10.0f * s);
                if (isdiag) e = (grow != gcol) ? e : 0.0f;   // diagonal exclusion
                rs[r] += e;
                cs[n] += e;
                if (inreg && (!isdiag || gcol > grow)) {     // strict upper triangle
                    const float d2 = fmaxf(2.0f - 2.0f * s, 0.0f);
                    lu += __expf(-2.0f * d2);
                }
            }
        }
        // row sums: reduce across the 16 lanes sharing (lane>>4)
#pragma unroll
        for (int off = 1; off < 16; off <<= 1) {
#pragma unroll
            for (int r = 0; r < 4; ++r) rs[r] += __shfl_xor(rs[r], off);
        }
        if ((lane & 15) == 0) {
#pragma unroll
            for (int r = 0; r < 4; ++r)
                atomicAdd(&rowsum[(wr << 6) + (m << 4) + rsub + r], rs[r]); // 2 adds/slot
        }
    }
    if (!isdiag) {
        // column sums: reduce across the 4 row-groups (lane bits 4-5)
#pragma unroll
        for (int off = 16; off < 64; off <<= 1) {
#pragma unroll
            for (int n = 0; n < 4; ++n) cs[n] += __shfl_xor(cs[n], off);
        }
        if (lane < 16) {
#pragma unroll
            for (int n = 0; n < 4; ++n)
                atomicAdd(&colsum[(wc << 6) + (n << 4) + lane], cs[n]);     // 2 adds/slot
        }
    }
#pragma unroll
    for (int off = 1; off < 64; off <<= 1) lu += __shfl_xor(lu, off);
    if (lane == 0) lured[wid] = lu;
    __syncthreads();
    if (t == 0) lup[(rt << 6) | ct] = lured[0] + lured[1] + lured[2] + lured[3];
    if (t < BM) partials[(size_t)(row0 + t) * NT + ct] = rowsum[t];
    else if (!isdiag) partials[(size_t)(col0 + t - BM) * NT + rt] = colsum[t - BM];
}

// --------- Kernel 3a: per-row denom -> log, 128 rows per block --------------
__global__ __launch_bounds__(128) void logred_kernel(
    const float* __restrict__ partials, double* __restrict__ red_log)
{
    const int t   = threadIdx.x;
    const int row = blockIdx.x * 128 + t;
    const float* p = partials + (size_t)row * NT;
    float dsum = 0.0f;
#pragma unroll
    for (int i = 0; i < NT; ++i) dsum += p[i];
    double l = log((double)dsum);
    __shared__ double sd[128];
    sd[t] = l;
    __syncthreads();
    for (int s = 64; s > 0; s >>= 1) {
        if (t < s) sd[t] += sd[t + s];
        __syncthreads();
    }
    if (t == 0) red_log[blockIdx.x] = sd[0];
}

// --------- Kernel 3b: final scalars --------------------------------------
__global__ __launch_bounds__(256) void final_kernel(
    const double* __restrict__ red_log, const float* __restrict__ pos,
    const float* __restrict__ lup, float* __restrict__ out)
{
    const int t = threadIdx.x;
    double dlog = 0.0, dpos = 0.0, ds1 = 0.0, ds2 = 0.0;
    if (t < 64) dlog = red_log[t];
    for (int i = t; i < NB; i += 256) dpos += (double)pos[i];
    for (int i = t; i < NT * NT; i += 256) {
        const int rt = i >> 6, ct = i & 63;
        if (rt > ct) continue;                 // only upper-tri tiles written
        const double v = (double)lup[i];
        if (rt < 16 && ct < 16) ds1 += v;
        else if (rt >= 16 && rt < 32 && ct >= 16 && ct < 32) ds2 += v;
    }
    __shared__ double sd[4][256];
    sd[0][t] = dlog; sd[1][t] = dpos; sd[2][t] = ds1; sd[3][t] = ds2;
    __syncthreads();
    for (int s = 128; s > 0; s >>= 1) {
        if (t < s) {
            sd[0][t] += sd[0][t + s]; sd[1][t] += sd[1][t + s];
            sd[2][t] += sd[2][t + s]; sd[3][t] += sd[3][t + s];
        }
        __syncthreads();
    }
    if (t == 0) {
        const double mean_pos = sd[1][0] / (double)NB;
        const double loss   = sd[0][0] / (double)N2 - mean_pos * 10.0;   // /TEMP
        const double lalign = 2.0 - 2.0 * mean_pos;
        const double C      = 2048.0 * 2047.0 * 0.5;
        const double lunif  = 0.5 * (log(sd[2][0] / C) + log(sd[3][0] / C));
        out[0] = (float)loss;
        out[1] = (float)lalign;
        out[2] = (float)lunif;
    }
}

extern "C" void kernel_launch(void* const* d_in, const int* in_sizes, int n_in,
                              void* d_out, int out_size, void* d_ws, size_t ws_size,
                              hipStream_t stream) {
    const float* p1 = (const float*)d_in[0];
    const float* p2 = (const float*)d_in[1];
    float* out = (float*)d_out;

    char* ws = (char*)d_ws;
    __hip_bfloat16* zb = (__hip_bfloat16*)ws;                          // 16 MB
    float*  partials   = (float*)(ws + ((size_t)16 << 20));            // 2 MB
    float*  pos        = (float*)(ws + ((size_t)18 << 20));            // 16 KB
    float*  lup        = (float*)(ws + ((size_t)18 << 20) + 16384);    // 16 KB
    double* red_log    = (double*)(ws + ((size_t)18 << 20) + 32768);   // 512 B

    hipLaunchKernelGGL(norm_kernel,  dim3(NB),     dim3(256), 0, stream, p1, p2, zb, pos);
    hipLaunchKernelGGL(sim_kernel,   dim3(NTILES), dim3(256), 0, stream, zb, partials, lup);
    hipLaunchKernelGGL(logred_kernel, dim3(64),    dim3(128), 0, stream, partials, red_log);
    hipLaunchKernelGGL(final_kernel, dim3(1),      dim3(256), 0, stream, red_log, pos, lup, out);
}

// Round 4
// 128.761 us; speedup vs baseline: 1.9143x; 1.1290x over previous
//
#include <hip/hip_runtime.h>
#include <hip/hip_bf16.h>
#include <math.h>

#define DIM 1024
#define NB  4096      // B
#define N2  8192      // 2B
#define BT  256       // output tile dim
#define BK  64        // K-tile
#define NT2 32        // N2 / BT
#define NTILES 528    // NT2*(NT2+1)/2 upper-triangular tiles

typedef float  f32x4  __attribute__((ext_vector_type(4)));
typedef __bf16 bf16x8 __attribute__((ext_vector_type(8)));

#define SB          __builtin_amdgcn_sched_barrier(0)
#define BARR        __builtin_amdgcn_s_barrier()
#define WAIT_LGKM0  asm volatile("s_waitcnt lgkmcnt(0)" ::: "memory")
#define WAIT_VM4    asm volatile("s_waitcnt vmcnt(4)"   ::: "memory")

__device__ __forceinline__ void gload_lds16(const __hip_bfloat16* g, __hip_bfloat16* l) {
    __builtin_amdgcn_global_load_lds((__attribute__((address_space(1))) void*)(g),
                                     (__attribute__((address_space(3))) void*)(l),
                                     16, 0, 0);
}

// ---------------- Kernel 1: normalize rows, emit bf16 z, positives ----------
__global__ __launch_bounds__(256) void norm_kernel(
    const float* __restrict__ p1, const float* __restrict__ p2,
    __hip_bfloat16* __restrict__ zb, float* __restrict__ pos)
{
    const int r = blockIdx.x;
    const int t = threadIdx.x;
    const float4 x1 = ((const float4*)(p1 + (size_t)r * DIM))[t];
    const float4 x2 = ((const float4*)(p2 + (size_t)r * DIM))[t];
    float s1  = x1.x*x1.x + x1.y*x1.y + x1.z*x1.z + x1.w*x1.w;
    float s2  = x2.x*x2.x + x2.y*x2.y + x2.z*x2.z + x2.w*x2.w;
    float s12 = x1.x*x2.x + x1.y*x2.y + x1.z*x2.z + x1.w*x2.w;
#pragma unroll
    for (int off = 1; off < 64; off <<= 1) {
        s1  += __shfl_xor(s1,  off);
        s2  += __shfl_xor(s2,  off);
        s12 += __shfl_xor(s12, off);
    }
    __shared__ float ls[3][4];
    const int wid = t >> 6;
    if ((t & 63) == 0) { ls[0][wid] = s1; ls[1][wid] = s2; ls[2][wid] = s12; }
    __syncthreads();
    s1  = ls[0][0] + ls[0][1] + ls[0][2] + ls[0][3];
    s2  = ls[1][0] + ls[1][1] + ls[1][2] + ls[1][3];
    s12 = ls[2][0] + ls[2][1] + ls[2][2] + ls[2][3];
    const float rn1 = 1.0f / fmaxf(sqrtf(s1), 1e-12f);
    const float rn2 = 1.0f / fmaxf(sqrtf(s2), 1e-12f);
    if (t == 0) pos[r] = s12 * rn1 * rn2;

    union { ushort4 u; __hip_bfloat16 h[4]; } o1, o2;
    o1.h[0] = __float2bfloat16(x1.x * rn1); o1.h[1] = __float2bfloat16(x1.y * rn1);
    o1.h[2] = __float2bfloat16(x1.z * rn1); o1.h[3] = __float2bfloat16(x1.w * rn1);
    o2.h[0] = __float2bfloat16(x2.x * rn2); o2.h[1] = __float2bfloat16(x2.y * rn2);
    o2.h[2] = __float2bfloat16(x2.z * rn2); o2.h[3] = __float2bfloat16(x2.w * rn2);
    ((ushort4*)zb)[(size_t)r * 256 + t]        = o1.u;
    ((ushort4*)zb)[(size_t)(NB + r) * 256 + t] = o2.u;
}

// ------- Kernel 2: 256^2 8-phase symmetric z.z^T + fused exp/lunif epilogue --
// 8 waves (2M x 4N), per-wave output 128x64. Double-buffered LDS (2x(A+B)=128K)
// with st-style XOR swizzle (linear gload_lds dest + pre-permuted global col +
// XOR'd ds_read). Counted vmcnt(4) at phases q3/q7 only. Dynamic tile stealing.
//
// Per-wave vmcnt ledger (loads = gload_lds instrs/wave; 2 per half-tile):
//   entering iter: 4 outstanding = (u+1).B0,B1
//   q0: +4 (u+1).A0A1 -> buf1.A (region consumed prev q7)
//   q1: +2 (u+2).B0  -> buf0.B (consumed q0)     q2: +2 (u+2).B1
//   q3: vmcnt(4): 12->4, drains ALL of tile u+1 before q4 reads it
//   q4: +4 (u+2).A0A1 -> buf0.A (consumed q3)
//   q5: +2 (u+3).B0  -> buf1.B (consumed q4)     q6: +2 (u+3).B1
//   q7: vmcnt(4): 12->4, drains ALL of tile u+2 before next-iter q0
// Job-end __syncthreads() = vmcnt(0) drain (flushes wrapped prefetches) before
// LDS reuse / next job restaging.
__global__ __launch_bounds__(512, 2) void sim_kernel(
    const __hip_bfloat16* __restrict__ zb,
    float* __restrict__ partials,    // [N2][NT2]
    float* __restrict__ lup,         // [NT2*NT2], rt<=ct slots only
    unsigned int* __restrict__ cnt)
{
    __shared__ __align__(16) __hip_bfloat16 buf[2][2][BT * BK]; // [dbuf][A/B]
    __shared__ int js;

    const int t    = threadIdx.x;
    const int lane = t & 63;
    const int wid  = t >> 6;       // 0..7
    const int wr   = wid >> 2;     // 0..1 (128-row half)
    const int wc   = wid & 3;      // 0..3 (64-col strip)

    const int fr   = lane & 15;
    const int xorb = (fr & 7) << 4;
    const int g16  = (lane >> 4) << 4;
    const int cb0  = g16 ^ xorb;
    const int cb1  = (64 | g16) ^ xorb;
    const int tcol = (((lane & 7) ^ ((lane >> 3) & 7)) << 3);
    const int lrow = lane >> 3;

    const char* Abase[2] = { (const char*)&buf[0][0][0] + (((wr << 7) + fr) << 7),
                             (const char*)&buf[1][0][0] + (((wr << 7) + fr) << 7) };
    const char* Bbase[2] = { (const char*)&buf[0][1][0] + (((wc << 6) + fr) << 7),
                             (const char*)&buf[1][1][0] + (((wc << 6) + fr) << 7) };

// stage one 1KB chunk (8 rows) of half-tile h, chunk l, K-tile v
#define STG(bsel, mat, h, l, base) \
    gload_lds16((base) + (size_t)(((h) * 128 + (l) * 8)) * DIM + (((v) & 15) << 6), \
                &buf[bsel][mat][((h) * 128 + wid * 16 + (l) * 8) * BK])
#define STAGE_A(bsel, h, vv) do { const int v = (vv); STG(bsel, 0, h, 0, arow); STG(bsel, 0, h, 1, arow); } while (0)
#define STAGE_B(bsel, h, vv) do { const int v = (vv); STG(bsel, 1, h, 0, bcol); STG(bsel, 1, h, 1, bcol); } while (0)

#define PH(B, Q, LOADB, STAGES, VMW) do { \
    if (LOADB) { \
        _Pragma("unroll") \
        for (int n = 0; n < 4; ++n) { \
            bv[n][0] = *(const bf16x8*)(Bbase[B] + (n << 11) + cb0); \
            bv[n][1] = *(const bf16x8*)(Bbase[B] + (n << 11) + cb1); \
        } \
    } \
    bf16x8 a00 = *(const bf16x8*)(Abase[B] + (((Q)*2+0) << 11) + cb0); \
    bf16x8 a01 = *(const bf16x8*)(Abase[B] + (((Q)*2+0) << 11) + cb1); \
    bf16x8 a10 = *(const bf16x8*)(Abase[B] + (((Q)*2+1) << 11) + cb0); \
    bf16x8 a11 = *(const bf16x8*)(Abase[B] + (((Q)*2+1) << 11) + cb1); \
    STAGES; \
    VMW; \
    SB; BARR; WAIT_LGKM0; SB; \
    __builtin_amdgcn_s_setprio(1); \
    _Pragma("unroll") \
    for (int n = 0; n < 4; ++n) { \
        acc[(Q)*2+0][n] = __builtin_amdgcn_mfma_f32_16x16x32_bf16(a00, bv[n][0], acc[(Q)*2+0][n], 0, 0, 0); \
        acc[(Q)*2+0][n] = __builtin_amdgcn_mfma_f32_16x16x32_bf16(a01, bv[n][1], acc[(Q)*2+0][n], 0, 0, 0); \
        acc[(Q)*2+1][n] = __builtin_amdgcn_mfma_f32_16x16x32_bf16(a10, bv[n][0], acc[(Q)*2+1][n], 0, 0, 0); \
        acc[(Q)*2+1][n] = __builtin_amdgcn_mfma_f32_16x16x32_bf16(a11, bv[n][1], acc[(Q)*2+1][n], 0, 0, 0); \
    } \
    __builtin_amdgcn_s_setprio(0); \
    SB; BARR; SB; \
} while (0)

    for (;;) {
        if (t == 0) js = (int)atomicAdd(cnt, 1u);
        __syncthreads();
        const int job = js;
        if (job >= NTILES) break;

        int rt = 0;
        while ((rt + 1) * NT2 - (((rt + 1) * rt) >> 1) <= job) ++rt;
        const int ct = rt + job - (rt * NT2 - ((rt * (rt - 1)) >> 1));
        const bool isdiag = (rt == ct);
        const int row0 = rt * BT;
        const int col0 = ct * BT;

        const __hip_bfloat16* arow = zb + (size_t)(row0 + wid * 16 + lrow) * DIM + tcol;
        const __hip_bfloat16* bcol = zb + (size_t)(col0 + wid * 16 + lrow) * DIM + tcol;

        f32x4 acc[8][4] = {};
        bf16x8 bv[4][2];

        // prologue: tile0 fully -> buf0; tile1 B -> buf1; drain tile0
        STAGE_B(0, 0, 0); STAGE_B(0, 1, 0);
        STAGE_A(0, 0, 0); STAGE_A(0, 1, 0);
        STAGE_B(1, 0, 1); STAGE_B(1, 1, 1);
        WAIT_VM4; SB; BARR; SB;

#pragma unroll 1
        for (int it = 0; it < 8; ++it) {
            const int u = it * 2;
            PH(0, 0, 1, { STAGE_A(1, 0, u + 1); STAGE_A(1, 1, u + 1); }, );
            PH(0, 1, 0, STAGE_B(0, 0, u + 2), );
            PH(0, 2, 0, STAGE_B(0, 1, u + 2), );
            PH(0, 3, 0, , WAIT_VM4);
            PH(1, 0, 1, { STAGE_A(0, 0, u + 2); STAGE_A(0, 1, u + 2); }, );
            PH(1, 1, 0, STAGE_B(1, 0, u + 3), );
            PH(1, 2, 0, STAGE_B(1, 1, u + 3), );
            PH(1, 3, 0, , WAIT_VM4);
        }

        __syncthreads();   // vmcnt(0)+lgkmcnt(0)+barrier: flush wrapped stages, free LDS

        // ---- epilogue: C/D layout col=lane&15, row=(lane>>4)*4+reg ----
        float* rsum4 = (float*)&buf[0][0][0];   // [256][4] per-(row,wc) slots
        float* csum2 = rsum4 + 1024;            // [256][2] per-(col,wr) slots
        float* lured = csum2 + 512;             // [8]

        const int  rsub  = (lane >> 4) << 2;
        const int  csub  = lane & 15;
        const bool inreg = (ct < 8) || (rt >= 8 && ct < 16);  // lunif sub-blocks
        const int  rbase = row0 + (wr << 7);
        const int  cbase = col0 + (wc << 6);

        float lu = 0.0f;
        float cs[4] = {0.0f, 0.0f, 0.0f, 0.0f};
#pragma unroll
        for (int m = 0; m < 8; ++m) {
            float rs[4] = {0.0f, 0.0f, 0.0f, 0.0f};
#pragma unroll
            for (int n = 0; n < 4; ++n) {
                const int gcol = cbase + (n << 4) + csub;
#pragma unroll
                for (int r = 0; r < 4; ++r) {
                    const int grow = rbase + (m << 4) + rsub + r;
                    const float s = acc[m][n][r];
                    float e = __expf(10.0f * s);
                    if (isdiag) e = (grow != gcol) ? e : 0.0f;
                    rs[r] += e;
                    cs[n] += e;
                    if (inreg && (!isdiag || gcol > grow)) {
                        const float d2 = fmaxf(2.0f - 2.0f * s, 0.0f);
                        lu += __expf(-2.0f * d2);
                    }
                }
            }
#pragma unroll
            for (int off = 1; off < 16; off <<= 1) {
#pragma unroll
                for (int r = 0; r < 4; ++r) rs[r] += __shfl_xor(rs[r], off);
            }
            if ((lane & 15) == 0) {
#pragma unroll
                for (int r = 0; r < 4; ++r)
                    rsum4[((wr << 7) + (m << 4) + rsub + r) * 4 + wc] = rs[r];
            }
        }
        if (!isdiag) {
#pragma unroll
            for (int off = 16; off < 64; off <<= 1) {
#pragma unroll
                for (int n = 0; n < 4; ++n) cs[n] += __shfl_xor(cs[n], off);
            }
            if (lane < 16) {
#pragma unroll
                for (int n = 0; n < 4; ++n)
                    csum2[((wc << 6) + (n << 4) + lane) * 2 + wr] = cs[n];
            }
        }
#pragma unroll
        for (int off = 1; off < 64; off <<= 1) lu += __shfl_xor(lu, off);
        if (lane == 0) lured[wid] = lu;
        __syncthreads();

        if (t == 0) {
            float s = 0.0f;
#pragma unroll
            for (int w = 0; w < 8; ++w) s += lured[w];
            lup[rt * NT2 + ct] = s;
        }
        if (t < 256) {
            const float* p = rsum4 + t * 4;
            partials[(size_t)(row0 + t) * NT2 + ct] = ((p[0] + p[1]) + p[2]) + p[3];
        } else if (!isdiag) {
            const float* p = csum2 + (t - 256) * 2;
            partials[(size_t)(col0 + t - 256) * NT2 + rt] = p[0] + p[1];
        }
        __syncthreads();   // before js overwrite / buf restage of next job
    }
#undef PH
#undef STAGE_A
#undef STAGE_B
#undef STG
}

// --------- Kernel 3a: per-row denom -> log, 128 rows per block --------------
__global__ __launch_bounds__(128) void logred_kernel(
    const float* __restrict__ partials, double* __restrict__ red_log)
{
    const int t   = threadIdx.x;
    const int row = blockIdx.x * 128 + t;
    const float* p = partials + (size_t)row * NT2;
    float dsum = 0.0f;
#pragma unroll
    for (int i = 0; i < NT2; ++i) dsum += p[i];
    double l = log((double)dsum);
    __shared__ double sd[128];
    sd[t] = l;
    __syncthreads();
    for (int s = 64; s > 0; s >>= 1) {
        if (t < s) sd[t] += sd[t + s];
        __syncthreads();
    }
    if (t == 0) red_log[blockIdx.x] = sd[0];
}

// --------- Kernel 3b: final scalars --------------------------------------
__global__ __launch_bounds__(256) void final_kernel(
    const double* __restrict__ red_log, const float* __restrict__ pos,
    const float* __restrict__ lup, float* __restrict__ out)
{
    const int t = threadIdx.x;
    double dlog = 0.0, dpos = 0.0, ds1 = 0.0, ds2 = 0.0;
    if (t < 64) dlog = red_log[t];
    for (int i = t; i < NB; i += 256) dpos += (double)pos[i];
    for (int i = t; i < NT2 * NT2; i += 256) {
        const int rt = i >> 5, ct = i & 31;
        if (rt > ct) continue;                 // only upper-tri tiles written
        const double v = (double)lup[i];
        if (rt < 8 && ct < 8) ds1 += v;
        else if (rt >= 8 && rt < 16 && ct >= 8 && ct < 16) ds2 += v;
    }
    __shared__ double sd[4][256];
    sd[0][t] = dlog; sd[1][t] = dpos; sd[2][t] = ds1; sd[3][t] = ds2;
    __syncthreads();
    for (int s = 128; s > 0; s >>= 1) {
        if (t < s) {
            sd[0][t] += sd[0][t + s]; sd[1][t] += sd[1][t + s];
            sd[2][t] += sd[2][t + s]; sd[3][t] += sd[3][t + s];
        }
        __syncthreads();
    }
    if (t == 0) {
        const double mean_pos = sd[1][0] / (double)NB;
        const double loss   = sd[0][0] / (double)N2 - mean_pos * 10.0;   // /TEMP
        const double lalign = 2.0 - 2.0 * mean_pos;
        const double C      = 2048.0 * 2047.0 * 0.5;
        const double lunif  = 0.5 * (log(sd[2][0] / C) + log(sd[3][0] / C));
        out[0] = (float)loss;
        out[1] = (float)lalign;
        out[2] = (float)lunif;
    }
}

extern "C" void kernel_launch(void* const* d_in, const int* in_sizes, int n_in,
                              void* d_out, int out_size, void* d_ws, size_t ws_size,
                              hipStream_t stream) {
    const float* p1 = (const float*)d_in[0];
    const float* p2 = (const float*)d_in[1];
    float* out = (float*)d_out;

    char* ws = (char*)d_ws;
    __hip_bfloat16* zb = (__hip_bfloat16*)ws;                            // 16 MB
    float*  partials   = (float*)(ws + ((size_t)16 << 20));              // 1 MB [8192][32]
    float*  pos        = (float*)(ws + ((size_t)17 << 20));              // 16 KB
    float*  lup        = (float*)(ws + ((size_t)17 << 20) + 16384);      // 4 KB
    double* red_log    = (double*)(ws + ((size_t)17 << 20) + 16384 + 4096); // 512 B
    unsigned int* cnt  = (unsigned int*)(ws + ((size_t)17 << 20) + 16384 + 4096 + 512);

    hipMemsetAsync(cnt, 0, sizeof(unsigned int), stream);
    hipLaunchKernelGGL(norm_kernel,   dim3(NB),  dim3(256), 0, stream, p1, p2, zb, pos);
    hipLaunchKernelGGL(sim_kernel,    dim3(256), dim3(512), 0, stream, zb, partials, lup, cnt);
    hipLaunchKernelGGL(logred_kernel, dim3(64),  dim3(128), 0, stream, partials, red_log);
    hipLaunchKernelGGL(final_kernel,  dim3(1),   dim3(256), 0, stream, red_log, pos, lup, out);
}

// Round 5
// 123.690 us; speedup vs baseline: 1.9928x; 1.0410x over previous
//
#include <hip/hip_runtime.h>
#include <hip/hip_bf16.h>
#include <math.h>

#define DIM 1024
#define NB  4096      // B
#define N2  8192      // 2B
#define BT  256       // output tile dim
#define BK  64        // K-tile
#define NT2 32        // N2 / BT
#define NTILES 528    // NT2*(NT2+1)/2 upper-triangular tiles

typedef float  f32x4  __attribute__((ext_vector_type(4)));
typedef __bf16 bf16x8 __attribute__((ext_vector_type(8)));

#define SB        __builtin_amdgcn_sched_barrier(0)
#define BARR      __builtin_amdgcn_s_barrier()
#define VM4       asm volatile("s_waitcnt vmcnt(4)" ::: "memory")
#define LG4       do { asm volatile("s_waitcnt lgkmcnt(4)" ::: "memory"); SB; } while (0)

__device__ __forceinline__ void gload_lds16(const __hip_bfloat16* g, __hip_bfloat16* l) {
    __builtin_amdgcn_global_load_lds((__attribute__((address_space(1))) void*)(g),
                                     (__attribute__((address_space(3))) void*)(l),
                                     16, 0, 0);
}

// ---------------- Kernel 1: normalize rows, emit bf16 z, positives ----------
__global__ __launch_bounds__(256) void norm_kernel(
    const float* __restrict__ p1, const float* __restrict__ p2,
    __hip_bfloat16* __restrict__ zb, float* __restrict__ pos)
{
    const int r = blockIdx.x;
    const int t = threadIdx.x;
    const float4 x1 = ((const float4*)(p1 + (size_t)r * DIM))[t];
    const float4 x2 = ((const float4*)(p2 + (size_t)r * DIM))[t];
    float s1  = x1.x*x1.x + x1.y*x1.y + x1.z*x1.z + x1.w*x1.w;
    float s2  = x2.x*x2.x + x2.y*x2.y + x2.z*x2.z + x2.w*x2.w;
    float s12 = x1.x*x2.x + x1.y*x2.y + x1.z*x2.z + x1.w*x2.w;
#pragma unroll
    for (int off = 1; off < 64; off <<= 1) {
        s1  += __shfl_xor(s1,  off);
        s2  += __shfl_xor(s2,  off);
        s12 += __shfl_xor(s12, off);
    }
    __shared__ float ls[3][4];
    const int wid = t >> 6;
    if ((t & 63) == 0) { ls[0][wid] = s1; ls[1][wid] = s2; ls[2][wid] = s12; }
    __syncthreads();
    s1  = ls[0][0] + ls[0][1] + ls[0][2] + ls[0][3];
    s2  = ls[1][0] + ls[1][1] + ls[1][2] + ls[1][3];
    s12 = ls[2][0] + ls[2][1] + ls[2][2] + ls[2][3];
    const float rn1 = 1.0f / fmaxf(sqrtf(s1), 1e-12f);
    const float rn2 = 1.0f / fmaxf(sqrtf(s2), 1e-12f);
    if (t == 0) pos[r] = s12 * rn1 * rn2;

    union { ushort4 u; __hip_bfloat16 h[4]; } o1, o2;
    o1.h[0] = __float2bfloat16(x1.x * rn1); o1.h[1] = __float2bfloat16(x1.y * rn1);
    o1.h[2] = __float2bfloat16(x1.z * rn1); o1.h[3] = __float2bfloat16(x1.w * rn1);
    o2.h[0] = __float2bfloat16(x2.x * rn2); o2.h[1] = __float2bfloat16(x2.y * rn2);
    o2.h[2] = __float2bfloat16(x2.z * rn2); o2.h[3] = __float2bfloat16(x2.w * rn2);
    ((ushort4*)zb)[(size_t)r * 256 + t]        = o1.u;
    ((ushort4*)zb)[(size_t)(NB + r) * 256 + t] = o2.u;
}

// ------- Kernel 2: 256^2 read-ahead-pipelined symmetric z.z^T ---------------
// 8 waves (2M x 4N). ONE barrier per phase; each phase issues NEXT phase's
// A-frag ds_reads (double-buffered as0/as1) and waits lgkmcnt(4) so the LDS
// pipe overlaps the MFMA burst. B-frags reload at each K-tile's first phase
// (P0/P4). Counted vmcnt(4) at P2/P6 only.
//
// Per-wave VMEM ledger (2 gloads per half-tile stage):
//   entering P0: 4 = B(u+1) [staged prev P5,P6]
//   P0: +4 A(u+1)->buf1.A -> 8     P1: +2 B0(u+2)->buf0.B -> 10
//   P2: +2 B1(u+2) -> 12; vmcnt(4) -> 4  [drains B(u+1),A(u+1); leaves B(u+2)]
//   P4: +4 A(u+2)->buf0.A -> 8     P5: +2 B0(u+3)->buf1.B -> 10
//   P6: +2 B1(u+3) -> 12; vmcnt(4) -> 4  [drains B(u+2),A(u+2); leaves B(u+3)]
// Reads of a freshly-staged region occur only after the vmcnt(4)+BARR that
// drains it (P3/P4 read buf1 after P2; P7/P0 read buf0 after P6).
__global__ __launch_bounds__(512, 2) void sim_kernel(
    const __hip_bfloat16* __restrict__ zb,
    float* __restrict__ partials,    // [N2][NT2]
    float* __restrict__ lup,         // [NT2*NT2], rt<=ct slots only
    unsigned int* __restrict__ cnt)
{
    __shared__ __align__(16) __hip_bfloat16 buf[2][2][BT * BK]; // [dbuf][A/B]
    __shared__ int js;

    const int t    = threadIdx.x;
    const int lane = t & 63;
    const int wid  = t >> 6;       // 0..7
    const int wr   = wid >> 2;     // 0..1 (128-row half)
    const int wc   = wid & 3;      // 0..3 (64-col strip)

    const int fr   = lane & 15;
    const int xorb = (fr & 7) << 4;
    const int g16  = (lane >> 4) << 4;
    const int cb0  = g16 ^ xorb;
    const int cb1  = (64 | g16) ^ xorb;
    const int tcol = (((lane & 7) ^ ((lane >> 3) & 7)) << 3);
    const int lrow = lane >> 3;

    const char* Abase[2] = { (const char*)&buf[0][0][0] + (((wr << 7) + fr) << 7),
                             (const char*)&buf[1][0][0] + (((wr << 7) + fr) << 7) };
    const char* Bbase[2] = { (const char*)&buf[0][1][0] + (((wc << 6) + fr) << 7),
                             (const char*)&buf[1][1][0] + (((wc << 6) + fr) << 7) };

#define STG(bsel, mat, h, l, base) \
    gload_lds16((base) + (size_t)(((h) * 128 + (l) * 8)) * DIM + (((v) & 15) << 6), \
                &buf[bsel][mat][((h) * 128 + wid * 16 + (l) * 8) * BK])
#define STAGE_A(bsel, h, vv) do { const int v = (vv); STG(bsel, 0, h, 0, arow); STG(bsel, 0, h, 1, arow); } while (0)
#define STAGE_B(bsel, h, vv) do { const int v = (vv); STG(bsel, 1, h, 0, bcol); STG(bsel, 1, h, 1, bcol); } while (0)

// load A-frag pair {MF0, MF0+1} of buffer BUF into set SET (consumed next phase)
#define LOADA(SET, BUF, MF0) do { \
    SET[0][0] = *(const bf16x8*)(Abase[BUF] + ((MF0) << 11) + cb0); \
    SET[0][1] = *(const bf16x8*)(Abase[BUF] + ((MF0) << 11) + cb1); \
    SET[1][0] = *(const bf16x8*)(Abase[BUF] + (((MF0) + 1) << 11) + cb0); \
    SET[1][1] = *(const bf16x8*)(Abase[BUF] + (((MF0) + 1) << 11) + cb1); \
} while (0)

#define LOADB(BUF) do { \
    _Pragma("unroll") \
    for (int n = 0; n < 4; ++n) { \
        bv[n][0] = *(const bf16x8*)(Bbase[BUF] + (n << 11) + cb0); \
        bv[n][1] = *(const bf16x8*)(Bbase[BUF] + (n << 11) + cb1); \
    } \
} while (0)

// 16 MFMA for m-pair P using operand set SET (8 independent, then 8 dist-8 deps)
#define MFMAP(P, SET) do { \
    __builtin_amdgcn_s_setprio(1); \
    _Pragma("unroll") \
    for (int n = 0; n < 4; ++n) { \
        acc[(P)*2+0][n] = __builtin_amdgcn_mfma_f32_16x16x32_bf16(SET[0][0], bv[n][0], acc[(P)*2+0][n], 0, 0, 0); \
        acc[(P)*2+1][n] = __builtin_amdgcn_mfma_f32_16x16x32_bf16(SET[1][0], bv[n][0], acc[(P)*2+1][n], 0, 0, 0); \
    } \
    _Pragma("unroll") \
    for (int n = 0; n < 4; ++n) { \
        acc[(P)*2+0][n] = __builtin_amdgcn_mfma_f32_16x16x32_bf16(SET[0][1], bv[n][1], acc[(P)*2+0][n], 0, 0, 0); \
        acc[(P)*2+1][n] = __builtin_amdgcn_mfma_f32_16x16x32_bf16(SET[1][1], bv[n][1], acc[(P)*2+1][n], 0, 0, 0); \
    } \
    __builtin_amdgcn_s_setprio(0); \
} while (0)

    for (;;) {
        if (t == 0) js = (int)atomicAdd(cnt, 1u);
        __syncthreads();
        const int job = js;
        if (job >= NTILES) break;

        int rt = 0;
        while ((rt + 1) * NT2 - (((rt + 1) * rt) >> 1) <= job) ++rt;
        const int ct = rt + job - (rt * NT2 - ((rt * (rt - 1)) >> 1));
        const bool isdiag = (rt == ct);
        const int row0 = rt * BT;
        const int col0 = ct * BT;

        const __hip_bfloat16* arow = zb + (size_t)(row0 + wid * 16 + lrow) * DIM + tcol;
        const __hip_bfloat16* bcol = zb + (size_t)(col0 + wid * 16 + lrow) * DIM + tcol;

        f32x4 acc[8][4] = {};
        bf16x8 bv[4][2];
        bf16x8 as0[2][2], as1[2][2];

        // prologue: tile0 -> buf0; tile1 B -> buf1; drain tile0; seed as0
        STAGE_B(0, 0, 0); STAGE_B(0, 1, 0);
        STAGE_A(0, 0, 0); STAGE_A(0, 1, 0);
        STAGE_B(1, 0, 1); STAGE_B(1, 1, 1);
        VM4; SB; BARR; SB;
        LOADA(as0, 0, 0);                 // 4 ds outstanding entering P0

#pragma unroll 1
        for (int it = 0; it < 8; ++it) {
            const int u = it * 2;
            // P0 (tile u, buf0, m0-1)
            BARR; SB;
            LOADB(0); LOADA(as1, 0, 2);
            STAGE_A(1, 0, u + 1); STAGE_A(1, 1, u + 1);
            LG4; MFMAP(0, as0);
            // P1 (m2-3)
            BARR; SB;
            LOADA(as0, 0, 4);
            STAGE_B(0, 0, u + 2);
            LG4; MFMAP(1, as1);
            // P2 (m4-5)
            BARR; SB;
            LOADA(as1, 0, 6);
            STAGE_B(0, 1, u + 2);
            VM4;
            LG4; MFMAP(2, as0);
            // P3 (m6-7) + read-ahead A(u+1,m0-1) from drained buf1
            BARR; SB;
            LOADA(as0, 1, 0);
            LG4; MFMAP(3, as1);
            // P4 (tile u+1, buf1, m0-1): reload B
            BARR; SB;
            LOADB(1); LOADA(as1, 1, 2);
            STAGE_A(0, 0, u + 2); STAGE_A(0, 1, u + 2);
            LG4; MFMAP(0, as0);
            // P5 (m2-3)
            BARR; SB;
            LOADA(as0, 1, 4);
            STAGE_B(1, 0, u + 3);
            LG4; MFMAP(1, as1);
            // P6 (m4-5)
            BARR; SB;
            LOADA(as1, 1, 6);
            STAGE_B(1, 1, u + 3);
            VM4;
            LG4; MFMAP(2, as0);
            // P7 (m6-7) + read-ahead A(u+2,m0-1) from drained buf0
            BARR; SB;
            LOADA(as0, 0, 0);
            LG4; MFMAP(3, as1);
        }

        __syncthreads();   // full vm/lgkm drain (flushes wrapped dummy stages)

        // ---- epilogue: C/D layout col=lane&15, row=(lane>>4)*4+reg ----
        float* rsum4 = (float*)&buf[0][0][0];   // [256][4] per-(row,wc) slots
        float* csum2 = rsum4 + 1024;            // [256][2] per-(col,wr) slots
        float* lured = csum2 + 512;             // [8]

        const int  rsub  = (lane >> 4) << 2;
        const int  csub  = lane & 15;
        const bool inreg = (ct < 8) || (rt >= 8 && ct < 16);  // lunif sub-blocks
        const int  rbase = row0 + (wr << 7);
        const int  cbase = col0 + (wc << 6);

        float lu = 0.0f;
        float cs[4] = {0.0f, 0.0f, 0.0f, 0.0f};
#pragma unroll
        for (int m = 0; m < 8; ++m) {
            float rs[4] = {0.0f, 0.0f, 0.0f, 0.0f};
#pragma unroll
            for (int n = 0; n < 4; ++n) {
                const int gcol = cbase + (n << 4) + csub;
#pragma unroll
                for (int r = 0; r < 4; ++r) {
                    const int grow = rbase + (m << 4) + rsub + r;
                    const float s = acc[m][n][r];
                    float e = __expf(10.0f * s);
                    if (isdiag) e = (grow != gcol) ? e : 0.0f;
                    rs[r] += e;
                    cs[n] += e;
                    if (inreg && (!isdiag || gcol > grow)) {
                        const float d2 = fmaxf(2.0f - 2.0f * s, 0.0f);
                        lu += __expf(-2.0f * d2);
                    }
                }
            }
#pragma unroll
            for (int off = 1; off < 16; off <<= 1) {
#pragma unroll
                for (int r = 0; r < 4; ++r) rs[r] += __shfl_xor(rs[r], off);
            }
            if ((lane & 15) == 0) {
#pragma unroll
                for (int r = 0; r < 4; ++r)
                    rsum4[((wr << 7) + (m << 4) + rsub + r) * 4 + wc] = rs[r];
            }
        }
        if (!isdiag) {
#pragma unroll
            for (int off = 16; off < 64; off <<= 1) {
#pragma unroll
                for (int n = 0; n < 4; ++n) cs[n] += __shfl_xor(cs[n], off);
            }
            if (lane < 16) {
#pragma unroll
                for (int n = 0; n < 4; ++n)
                    csum2[((wc << 6) + (n << 4) + lane) * 2 + wr] = cs[n];
            }
        }
#pragma unroll
        for (int off = 1; off < 64; off <<= 1) lu += __shfl_xor(lu, off);
        if (lane == 0) lured[wid] = lu;
        __syncthreads();

        if (t == 0) {
            float s = 0.0f;
#pragma unroll
            for (int w = 0; w < 8; ++w) s += lured[w];
            lup[rt * NT2 + ct] = s;
        }
        if (t < 256) {
            const float* p = rsum4 + t * 4;
            partials[(size_t)(row0 + t) * NT2 + ct] = ((p[0] + p[1]) + p[2]) + p[3];
        } else if (!isdiag) {
            const float* p = csum2 + (t - 256) * 2;
            partials[(size_t)(col0 + t - 256) * NT2 + rt] = p[0] + p[1];
        }
        __syncthreads();   // before js overwrite / buf restage of next job
    }
#undef MFMAP
#undef LOADB
#undef LOADA
#undef STAGE_A
#undef STAGE_B
#undef STG
}

// --------- Kernel 3a: per-row denom -> log, 128 rows per block --------------
__global__ __launch_bounds__(128) void logred_kernel(
    const float* __restrict__ partials, double* __restrict__ red_log)
{
    const int t   = threadIdx.x;
    const int row = blockIdx.x * 128 + t;
    const float* p = partials + (size_t)row * NT2;
    float dsum = 0.0f;
#pragma unroll
    for (int i = 0; i < NT2; ++i) dsum += p[i];
    double l = log((double)dsum);
    __shared__ double sd[128];
    sd[t] = l;
    __syncthreads();
    for (int s = 64; s > 0; s >>= 1) {
        if (t < s) sd[t] += sd[t + s];
        __syncthreads();
    }
    if (t == 0) red_log[blockIdx.x] = sd[0];
}

// --------- Kernel 3b: final scalars --------------------------------------
__global__ __launch_bounds__(256) void final_kernel(
    const double* __restrict__ red_log, const float* __restrict__ pos,
    const float* __restrict__ lup, float* __restrict__ out)
{
    const int t = threadIdx.x;
    double dlog = 0.0, dpos = 0.0, ds1 = 0.0, ds2 = 0.0;
    if (t < 64) dlog = red_log[t];
    for (int i = t; i < NB; i += 256) dpos += (double)pos[i];
    for (int i = t; i < NT2 * NT2; i += 256) {
        const int rt = i >> 5, ct = i & 31;
        if (rt > ct) continue;                 // only upper-tri tiles written
        const double v = (double)lup[i];
        if (rt < 8 && ct < 8) ds1 += v;
        else if (rt >= 8 && rt < 16 && ct >= 8 && ct < 16) ds2 += v;
    }
    __shared__ double sd[4][256];
    sd[0][t] = dlog; sd[1][t] = dpos; sd[2][t] = ds1; sd[3][t] = ds2;
    __syncthreads();
    for (int s = 128; s > 0; s >>= 1) {
        if (t < s) {
            sd[0][t] += sd[0][t + s]; sd[1][t] += sd[1][t + s];
            sd[2][t] += sd[2][t + s]; sd[3][t] += sd[3][t + s];
        }
        __syncthreads();
    }
    if (t == 0) {
        const double mean_pos = sd[1][0] / (double)NB;
        const double loss   = sd[0][0] / (double)N2 - mean_pos * 10.0;   // /TEMP
        const double lalign = 2.0 - 2.0 * mean_pos;
        const double C      = 2048.0 * 2047.0 * 0.5;
        const double lunif  = 0.5 * (log(sd[2][0] / C) + log(sd[3][0] / C));
        out[0] = (float)loss;
        out[1] = (float)lalign;
        out[2] = (float)lunif;
    }
}

extern "C" void kernel_launch(void* const* d_in, const int* in_sizes, int n_in,
                              void* d_out, int out_size, void* d_ws, size_t ws_size,
                              hipStream_t stream) {
    const float* p1 = (const float*)d_in[0];
    const float* p2 = (const float*)d_in[1];
    float* out = (float*)d_out;

    char* ws = (char*)d_ws;
    __hip_bfloat16* zb = (__hip_bfloat16*)ws;                            // 16 MB
    float*  partials   = (float*)(ws + ((size_t)16 << 20));              // 1 MB [8192][32]
    float*  pos        = (float*)(ws + ((size_t)17 << 20));              // 16 KB
    float*  lup        = (float*)(ws + ((size_t)17 << 20) + 16384);      // 4 KB
    double* red_log    = (double*)(ws + ((size_t)17 << 20) + 16384 + 4096); // 512 B
    unsigned int* cnt  = (unsigned int*)(ws + ((size_t)17 << 20) + 16384 + 4096 + 512);

    hipMemsetAsync(cnt, 0, sizeof(unsigned int), stream);
    hipLaunchKernelGGL(norm_kernel,   dim3(NB),  dim3(256), 0, stream, p1, p2, zb, pos);
    hipLaunchKernelGGL(sim_kernel,    dim3(256), dim3(512), 0, stream, zb, partials, lup, cnt);
    hipLaunchKernelGGL(logred_kernel, dim3(64),  dim3(128), 0, stream, partials, red_log);
    hipLaunchKernelGGL(final_kernel,  dim3(1),   dim3(256), 0, stream, red_log, pos, lup, out);
}